// Round 5
// baseline (2186.530 us; speedup 1.0000x reference)
//
#include <hip/hip_runtime.h>

// GIN (5 layers) + BN + pool + MLP head, fused pipeline for MI355X. Round 5.
// Changes vs R4 (prep 104us: ELL 2B-scatter write-amp 57MB + 800k fabric atomics;
// layers ~80us bound by L2-miss bytes of the fp32 gather):
//  - features stored bf16 (fp32 math): halves gather miss-path bytes, hin fits
//    per-XCD L2 much better; halves hout/pool traffic too
//  - ELL replaced by dst-bucketed edge lists (bucket = dst>>6 = one layer tile):
//    per edge 1 hot-counter atomic + one packed 4B store with line locality;
//    layer gather reads bucket contiguously, ds_add_f32 into LDS tile rows,
//    deg re-derived in LDS (deg array + pad pass gone)

constexpr int N = 50000;
constexpr int E = 800000;
constexpr int G = 128;
constexpr int CAP = 1280;            // bucket capacity (mean 1023, +8 sigma)
constexpr int NB = (N + 63) / 64;    // 782 buckets / layer tiles
constexpr int SSPLIT = 16;           // stats accumulator copies
constexpr float BN_EPS = 1e-5f;

__device__ inline float4 ld4(const float* p) { return *(const float4*)p; }
__device__ inline void st4(float* p, float4 v) { *(float4*)p = v; }

__device__ inline float bf2f(unsigned short u) {
    union { unsigned u32; float f; } c; c.u32 = ((unsigned)u) << 16; return c.f;
}
__device__ inline unsigned short f2bf(float f) {
    union { float f; unsigned u; } c; c.f = f;
    unsigned r = c.u + 0x7fff + ((c.u >> 16) & 1);   // round-to-nearest-even
    return (unsigned short)(r >> 16);
}

// blocks [0,EB): 1 edge/thread -> bucket scatter. blocks [EB,EB+XB): xw = x@W1a (bf16 out).
__global__ __launch_bounds__(256) void prep_kernel(
    const int* __restrict__ ei, int* __restrict__ cnt, unsigned* __restrict__ bkt,
    const float* __restrict__ x, const float* __restrict__ W,
    unsigned short* __restrict__ out, int EB)
{
    int tid = threadIdx.x;
    if (blockIdx.x < EB) {
        int e = blockIdx.x * 256 + tid;
        if (e < E) {
            int s = ei[e];
            int d = ei[E + e];
            int b = d >> 6;
            int slot = atomicAdd(&cnt[b], 1);
            if (slot < CAP)
                bkt[(size_t)b * CAP + slot] = ((unsigned)s << 6) | (unsigned)(d & 63);
        }
        return;
    }
    // ---- xw part: tile of 64 nodes ----
    int base = (blockIdx.x - EB) * 64;
    int ty = tid >> 4, tx = tid & 15;

    float acc[4][4];
#pragma unroll
    for (int r = 0; r < 4; r++)
#pragma unroll
        for (int cc = 0; cc < 4; cc++) acc[r][cc] = 0.f;

    int rr[4];
#pragma unroll
    for (int r = 0; r < 4; r++) rr[r] = min(base + 4 * ty + r, N - 1);

#pragma unroll 4
    for (int c = 0; c < 128; c++) {
        float4 w4 = ld4(W + c * 64 + 4 * tx);
#pragma unroll
        for (int r = 0; r < 4; r++) {
            float a = x[(size_t)rr[r] * 128 + c];
            acc[r][0] += a * w4.x; acc[r][1] += a * w4.y;
            acc[r][2] += a * w4.z; acc[r][3] += a * w4.w;
        }
    }
#pragma unroll
    for (int r = 0; r < 4; r++) {
        int node = base + 4 * ty + r;
        if (node < N) {
            ushort4 s;
            s.x = f2bf(acc[r][0]); s.y = f2bf(acc[r][1]);
            s.z = f2bf(acc[r][2]); s.w = f2bf(acc[r][3]);
            *(ushort4*)(out + (size_t)node * 64 + 4 * tx) = s;
        }
    }
}

// Fused GIN layer, 64-node tile == one bucket. hin/hout are bf16 [N][64].
// FIRST:  v = relu(own + sum_src + b1a)  then GEMM2(W2,b2)+relu
// !FIRST: v = sc*(own+sum) + (1+deg)*sh, GEMM1+relu (in-place), GEMM2+relu
// statsPrev/statsOut: SSPLIT x 128 fp32 accumulators (sum | sumsq).
template <bool FIRST>
__global__ __launch_bounds__(256) void layer_kernel(
    const unsigned short* __restrict__ hin, const unsigned* __restrict__ bkt,
    const int* __restrict__ cnt,
    const float* __restrict__ statsPrev, const float* __restrict__ gamma,
    const float* __restrict__ beta, const float* __restrict__ bias0,
    const float* __restrict__ W1, const float* __restrict__ b1,
    const float* __restrict__ W2, const float* __restrict__ b2,
    unsigned short* __restrict__ hout, float* __restrict__ statsOut)
{
    __shared__ float sV[64 * 68];
    __shared__ int   sDeg[64];
    __shared__ float sStat[128];

    int tid = threadIdx.x, lane = tid & 63, wv = tid >> 6;
    if (tid < 128) sStat[tid] = 0.f;
    if (tid < 64)  sDeg[tid] = 0;

    int base = blockIdx.x * 64;

    // per-lane (channel = lane) epilogue params
    float r_sc = 1.f, r_sh = 0.f, r_b0 = 0.f;
    if constexpr (FIRST) {
        r_b0 = bias0[lane];
    } else {
        float s1 = 0.f, s2 = 0.f;
#pragma unroll
        for (int s = 0; s < SSPLIT; s++) {
            s1 += statsPrev[s * 128 + lane];
            s2 += statsPrev[s * 128 + 64 + lane];
        }
        float mean = s1 * (1.f / N);
        float var  = s2 * (1.f / N) - mean * mean;
        r_sc = gamma[lane] * rsqrtf(var + BN_EPS);
        r_sh = beta[lane] - mean * r_sc;
    }

    // ---- init: own contribution into sV rows ----
#pragma unroll
    for (int i = 0; i < 16; i++) {
        int r = wv * 16 + i;
        int node = base + r;
        sV[r * 68 + lane] = (node < N) ? bf2f(hin[(size_t)node * 64 + lane]) : 0.f;
    }
    __syncthreads();

    // ---- gather: process bucket entries, ds_add into tile rows ----
    int m = min(cnt[blockIdx.x], CAP);
    const unsigned* bk = bkt + (size_t)blockIdx.x * CAP;
    for (int j0 = wv * 64; j0 < m; j0 += 256) {
        int have = min(64, m - j0);
        unsigned ent = 0;
        if (lane < have) {
            ent = bk[j0 + lane];
            atomicAdd(&sDeg[ent & 63], 1);
        }
        int k = 0;
        for (; k + 8 <= have; k += 8) {
            unsigned e0 = (unsigned)__builtin_amdgcn_readlane((int)ent, k + 0);
            unsigned e1 = (unsigned)__builtin_amdgcn_readlane((int)ent, k + 1);
            unsigned e2 = (unsigned)__builtin_amdgcn_readlane((int)ent, k + 2);
            unsigned e3 = (unsigned)__builtin_amdgcn_readlane((int)ent, k + 3);
            unsigned e4 = (unsigned)__builtin_amdgcn_readlane((int)ent, k + 4);
            unsigned e5 = (unsigned)__builtin_amdgcn_readlane((int)ent, k + 5);
            unsigned e6 = (unsigned)__builtin_amdgcn_readlane((int)ent, k + 6);
            unsigned e7 = (unsigned)__builtin_amdgcn_readlane((int)ent, k + 7);
            float v0 = bf2f(hin[((size_t)(e0 >> 6)) * 64 + lane]);
            float v1 = bf2f(hin[((size_t)(e1 >> 6)) * 64 + lane]);
            float v2 = bf2f(hin[((size_t)(e2 >> 6)) * 64 + lane]);
            float v3 = bf2f(hin[((size_t)(e3 >> 6)) * 64 + lane]);
            float v4 = bf2f(hin[((size_t)(e4 >> 6)) * 64 + lane]);
            float v5 = bf2f(hin[((size_t)(e5 >> 6)) * 64 + lane]);
            float v6 = bf2f(hin[((size_t)(e6 >> 6)) * 64 + lane]);
            float v7 = bf2f(hin[((size_t)(e7 >> 6)) * 64 + lane]);
            atomicAdd(&sV[(e0 & 63) * 68 + lane], v0);
            atomicAdd(&sV[(e1 & 63) * 68 + lane], v1);
            atomicAdd(&sV[(e2 & 63) * 68 + lane], v2);
            atomicAdd(&sV[(e3 & 63) * 68 + lane], v3);
            atomicAdd(&sV[(e4 & 63) * 68 + lane], v4);
            atomicAdd(&sV[(e5 & 63) * 68 + lane], v5);
            atomicAdd(&sV[(e6 & 63) * 68 + lane], v6);
            atomicAdd(&sV[(e7 & 63) * 68 + lane], v7);
        }
        for (; k < have; k++) {
            unsigned e0 = (unsigned)__builtin_amdgcn_readlane((int)ent, k);
            float v0 = bf2f(hin[((size_t)(e0 >> 6)) * 64 + lane]);
            atomicAdd(&sV[(e0 & 63) * 68 + lane], v0);
        }
    }
    __syncthreads();

    // ---- epilogue transform: V = relu(sum + b0) | sc*sum + (1+deg)*sh ----
#pragma unroll
    for (int i = 0; i < 16; i++) {
        int r = wv * 16 + i;
        int node = base + r;
        float sum = sV[r * 68 + lane];
        float v = 0.f;
        if (node < N) {
            if constexpr (FIRST) v = fmaxf(sum + r_b0, 0.f);
            else                 v = r_sc * sum + (float)(1 + sDeg[r]) * r_sh;
        }
        sV[r * 68 + lane] = v;
    }
    __syncthreads();

    int ty = tid >> 4, tx = tid & 15;

    if constexpr (!FIRST) {
        // ---- GEMM1: H = relu(V @ W1 + b1), in-place into sV ----
        float acc[4][4];
#pragma unroll
        for (int cc = 0; cc < 4; cc++) {
            float b = b1[4 * tx + cc];
            acc[0][cc] = b; acc[1][cc] = b; acc[2][cc] = b; acc[3][cc] = b;
        }
#pragma unroll 4
        for (int c = 0; c < 64; c++) {
            float4 w4 = ld4(W1 + c * 64 + 4 * tx);
#pragma unroll
            for (int r = 0; r < 4; r++) {
                float a = sV[(4 * ty + r) * 68 + c];
                acc[r][0] += a * w4.x; acc[r][1] += a * w4.y;
                acc[r][2] += a * w4.z; acc[r][3] += a * w4.w;
            }
        }
        __syncthreads();
#pragma unroll
        for (int r = 0; r < 4; r++)
            st4(sV + (4 * ty + r) * 68 + 4 * tx,
                make_float4(fmaxf(acc[r][0], 0.f), fmaxf(acc[r][1], 0.f),
                            fmaxf(acc[r][2], 0.f), fmaxf(acc[r][3], 0.f)));
        __syncthreads();
    }

    // ---- GEMM2: O = relu(V @ W2 + b2), store bf16, stats ----
    float acc[4][4];
#pragma unroll
    for (int cc = 0; cc < 4; cc++) {
        float b = b2[4 * tx + cc];
        acc[0][cc] = b; acc[1][cc] = b; acc[2][cc] = b; acc[3][cc] = b;
    }
#pragma unroll 4
    for (int c = 0; c < 64; c++) {
        float4 w4 = ld4(W2 + c * 64 + 4 * tx);
#pragma unroll
        for (int r = 0; r < 4; r++) {
            float a = sV[(4 * ty + r) * 68 + c];
            acc[r][0] += a * w4.x; acc[r][1] += a * w4.y;
            acc[r][2] += a * w4.z; acc[r][3] += a * w4.w;
        }
    }
#pragma unroll
    for (int r = 0; r < 4; r++) {
        int node = base + 4 * ty + r;
        if (node < N) {
            float o0 = fmaxf(acc[r][0], 0.f), o1 = fmaxf(acc[r][1], 0.f);
            float o2 = fmaxf(acc[r][2], 0.f), o3 = fmaxf(acc[r][3], 0.f);
            acc[r][0] = o0; acc[r][1] = o1; acc[r][2] = o2; acc[r][3] = o3;
            ushort4 s;
            s.x = f2bf(o0); s.y = f2bf(o1); s.z = f2bf(o2); s.w = f2bf(o3);
            *(ushort4*)(hout + (size_t)node * 64 + 4 * tx) = s;
        } else {
            acc[r][0] = acc[r][1] = acc[r][2] = acc[r][3] = 0.f;
        }
    }
#pragma unroll
    for (int cc = 0; cc < 4; cc++) {
        float s = 0.f, q = 0.f;
#pragma unroll
        for (int r = 0; r < 4; r++) { s += acc[r][cc]; q += acc[r][cc] * acc[r][cc]; }
        atomicAdd(&sStat[4 * tx + cc], s);
        atomicAdd(&sStat[64 + 4 * tx + cc], q);
    }
    __syncthreads();
    if (tid < 128)
        atomicAdd(&statsOut[(blockIdx.x & (SSPLIT - 1)) * 128 + tid], sStat[tid]);
}

// pooled[g] = sc*sum_{n in g} h[n] + cnt*sh; z=relu(p@fc1+b1); z@fc2+b2; log_softmax
__global__ __launch_bounds__(1024) void pool_head_kernel(
    const unsigned short* __restrict__ h, const int* __restrict__ batch,
    const float* __restrict__ stats, const float* __restrict__ gamma, const float* __restrict__ beta,
    const float* __restrict__ fc1w, const float* __restrict__ fc1b,
    const float* __restrict__ fc2w, const float* __restrict__ fc2b,
    float* __restrict__ out)
{
    __shared__ float sacc[16][64];
    __shared__ float sp[64];
    __shared__ float sz[64];
    __shared__ float so[10];

    int g = blockIdx.x;
    int lane = threadIdx.x & 63, wv = threadIdx.x >> 6;   // 16 waves

    int start, end;
    {
        int lo = 0, hi = N;
        while (lo < hi) { int mid = (lo + hi) >> 1; if (batch[mid] < g) lo = mid + 1; else hi = mid; }
        start = lo;
        lo = start; hi = N;
        while (lo < hi) { int mid = (lo + hi) >> 1; if (batch[mid] < g + 1) lo = mid + 1; else hi = mid; }
        end = lo;
    }

    float acc = 0.f;
    for (int node = start + wv; node < end; node += 16)
        acc += bf2f(h[(size_t)node * 64 + lane]);
    sacc[wv][lane] = acc;
    __syncthreads();

    if (wv == 0) {
        float s1 = 0.f, s2 = 0.f;
#pragma unroll
        for (int s = 0; s < SSPLIT; s++) {
            s1 += stats[s * 128 + lane];
            s2 += stats[s * 128 + 64 + lane];
        }
        float mean = s1 * (1.f / N);
        float var  = s2 * (1.f / N) - mean * mean;
        float sc = gamma[lane] * rsqrtf(var + BN_EPS);
        float sh = beta[lane] - mean * sc;
        float t = 0.f;
#pragma unroll
        for (int w = 0; w < 16; w++) t += sacc[w][lane];
        sp[lane] = sc * t + (float)(end - start) * sh;
    }
    __syncthreads();
    if (wv == 0) {
        float a = fc1b[lane];
#pragma unroll
        for (int c = 0; c < 64; c++) a += sp[c] * fc1w[c * 64 + lane];
        sz[lane] = fmaxf(a, 0.f);
    }
    __syncthreads();
    if (wv == 0 && lane < 10) {
        float z = fc2b[lane];
#pragma unroll
        for (int j = 0; j < 64; j++) z += sz[j] * fc2w[j * 10 + lane];
        so[lane] = z;
    }
    __syncthreads();
    if (wv == 0 && lane < 10) {
        float m = -1e30f;
#pragma unroll
        for (int c = 0; c < 10; c++) m = fmaxf(m, so[c]);
        float s = 0.f;
#pragma unroll
        for (int c = 0; c < 10; c++) s += expf(so[c] - m);
        out[g * 10 + lane] = so[lane] - m - logf(s);
    }
}

extern "C" void kernel_launch(void* const* d_in, const int* in_sizes, int n_in,
                              void* d_out, int out_size, void* d_ws, size_t ws_size,
                              hipStream_t stream)
{
    const float* x    = (const float*)d_in[0];
    const int*   ei   = (const int*)  d_in[1];
    const int*   batch= (const int*)  d_in[2];
    const float* W1a  = (const float*)d_in[3];
    const float* b1a  = (const float*)d_in[4];
    const float* W1b  = (const float*)d_in[5];
    const float* b1b  = (const float*)d_in[6];
    const float* Wa   = (const float*)d_in[7];
    const float* ba   = (const float*)d_in[8];
    const float* Wb   = (const float*)d_in[9];
    const float* bb   = (const float*)d_in[10];
    const float* gammas = (const float*)d_in[11];
    const float* betas  = (const float*)d_in[12];
    const float* fc1w = (const float*)d_in[13];
    const float* fc1b = (const float*)d_in[14];
    const float* fc2w = (const float*)d_in[15];
    const float* fc2b = (const float*)d_in[16];
    float* out = (float*)d_out;

    // workspace carve
    char* w = (char*)d_ws;
    int*            cnt   = (int*)w;                        // NB ints   @0        (zeroed)
    float*          stats = (float*)(w + 4096);             // 5*16*128  @4096     (zeroed)
    unsigned*       bkt   = (unsigned*)(w + 45056);         // NB*CAP u32 (4.0 MB)
    unsigned short* bufA  = (unsigned short*)(w + 4048896); // N*64 bf16 (6.4 MB)
    unsigned short* bufB  = (unsigned short*)(w + 10448896);// N*64 bf16 (6.4 MB)

    hipMemsetAsync(d_ws, 0, 45056, stream);                 // cnt + stats

    int EB = (E + 255) / 256;            // 3125 edge blocks
    int XB = NB;                         // 782 xw blocks
    prep_kernel<<<EB + XB, 256, 0, stream>>>(ei, cnt, bkt, x, W1a, bufA, EB);

    const int SST = SSPLIT * 128;
    layer_kernel<true><<<NB, 256, 0, stream>>>(
        bufA, bkt, cnt, nullptr, nullptr, nullptr, b1a,
        nullptr, nullptr, W1b, b1b, bufB, stats);

    layer_kernel<false><<<NB, 256, 0, stream>>>(
        bufB, bkt, cnt, stats, gammas, betas, nullptr,
        Wa, ba, Wb, bb, bufA, stats + SST);

    layer_kernel<false><<<NB, 256, 0, stream>>>(
        bufA, bkt, cnt, stats + SST, gammas + 64, betas + 64, nullptr,
        Wa + 4096, ba + 64, Wb + 4096, bb + 64, bufB, stats + 2 * SST);

    layer_kernel<false><<<NB, 256, 0, stream>>>(
        bufB, bkt, cnt, stats + 2 * SST, gammas + 128, betas + 128, nullptr,
        Wa + 8192, ba + 128, Wb + 8192, bb + 128, bufA, stats + 3 * SST);

    layer_kernel<false><<<NB, 256, 0, stream>>>(
        bufA, bkt, cnt, stats + 3 * SST, gammas + 192, betas + 192, nullptr,
        Wa + 12288, ba + 192, Wb + 12288, bb + 192, bufB, stats + 4 * SST);

    pool_head_kernel<<<G, 1024, 0, stream>>>(
        bufB, batch, stats + 4 * SST, gammas + 256, betas + 256,
        fc1w, fc1b, fc2w, fc2b, out);
}

// Round 7
// 638.238 us; speedup vs baseline: 3.4259x; 3.4259x over previous
//
#include <hip/hip_runtime.h>
#include <hip/hip_fp16.h>

// GIN (5 layers) + BN + pool + MLP head, fused pipeline for MI355X. Round 7.
// Changes vs R6 (failed absmax 0.4375 vs 0.4175 — bf16 h-storage at threshold edge):
//  - feature storage fp16 (same 2B/elem, 8x less rounding err than bf16);
//    all math fp32. Predicted absmax ~0.05.
//  - pool_head dead loop removed; gamma/beta layer indexing fixed (layer i+2
//    folds BN_i).
// Structure kept from R6: bucket scatter prep -> bucket->ELL conv ->
// per layer {high-occupancy agg (wave per node pair, 2KB in flight),
// 64-tile mlp (GEMMs)} -> fused pool+head.

constexpr int N = 50000;
constexpr int E = 800000;
constexpr int G = 128;
constexpr int CAP = 1280;            // bucket capacity (mean 1023, +8 sigma)
constexpr int NB = (N + 63) / 64;    // 782 buckets / mlp tiles
constexpr int SSPLIT = 16;           // stats accumulator copies
constexpr float BN_EPS = 1e-5f;

__device__ inline float4 ld4(const float* p) { return *(const float4*)p; }
__device__ inline void st4(float* p, float4 v) { *(float4*)p = v; }

__device__ inline float2 h2f2(unsigned v) {
    __half2 h; *(unsigned*)&h = v; return __half22float2(h);
}
__device__ inline unsigned short f2h(float f) {
    __half h = __float2half_rn(f); return *(unsigned short*)&h;
}
__device__ inline float h2f(unsigned short u) {
    __half h; *(unsigned short*)&h = u; return __half2float(h);
}

// blocks [0,EB): 1 edge/thread -> bucket scatter. blocks [EB,EB+NB): xw = x@W1a (fp16).
__global__ __launch_bounds__(256) void prep_kernel(
    const int* __restrict__ ei, int* __restrict__ cnt, unsigned* __restrict__ bkt,
    const float* __restrict__ x, const float* __restrict__ W,
    unsigned short* __restrict__ out, int EB)
{
    int tid = threadIdx.x;
    if (blockIdx.x < EB) {
        int e = blockIdx.x * 256 + tid;
        if (e < E) {
            int s = ei[e];
            int d = ei[E + e];
            int b = d >> 6;
            int slot = atomicAdd(&cnt[b], 1);
            if (slot < CAP)
                bkt[(size_t)b * CAP + slot] = ((unsigned)s << 6) | (unsigned)(d & 63);
        }
        return;
    }
    int base = (blockIdx.x - EB) * 64;
    int ty = tid >> 4, tx = tid & 15;

    float acc[4][4];
#pragma unroll
    for (int r = 0; r < 4; r++)
#pragma unroll
        for (int cc = 0; cc < 4; cc++) acc[r][cc] = 0.f;

    int rr[4];
#pragma unroll
    for (int r = 0; r < 4; r++) rr[r] = min(base + 4 * ty + r, N - 1);

#pragma unroll 4
    for (int c = 0; c < 128; c++) {
        float4 w4 = ld4(W + c * 64 + 4 * tx);
#pragma unroll
        for (int r = 0; r < 4; r++) {
            float a = x[(size_t)rr[r] * 128 + c];
            acc[r][0] += a * w4.x; acc[r][1] += a * w4.y;
            acc[r][2] += a * w4.z; acc[r][3] += a * w4.w;
        }
    }
#pragma unroll
    for (int r = 0; r < 4; r++) {
        int node = base + 4 * ty + r;
        if (node < N) {
            ushort4 s;
            s.x = f2h(acc[r][0]); s.y = f2h(acc[r][1]);
            s.z = f2h(acc[r][2]); s.w = f2h(acc[r][3]);
            *(ushort4*)(out + (size_t)node * 64 + 4 * tx) = s;
        }
    }
}

// bucket b -> ELL rows for nodes [b*64, b*64+64): slot alloc via LDS counters,
// write deg, pad rows to mult-8 with sentinel N.
__global__ __launch_bounds__(256) void conv_kernel(
    const unsigned* __restrict__ bkt, const int* __restrict__ cnt,
    unsigned short* __restrict__ ell, int* __restrict__ deg)
{
    __shared__ int sCnt[64];
    int b = blockIdx.x, tid = threadIdx.x;
    if (tid < 64) sCnt[tid] = 0;
    __syncthreads();
    int m = min(cnt[b], CAP);
    const unsigned* bk = bkt + (size_t)b * CAP;
    for (int i = tid; i < m; i += 256) {
        unsigned e = bk[i];
        int dl = e & 63;
        int slot = atomicAdd(&sCnt[dl], 1);
        if (slot < 64)
            ell[(size_t)(b * 64 + dl) * 64 + slot] = (unsigned short)(e >> 6);
    }
    __syncthreads();
    if (tid < 64) {
        int node = b * 64 + tid;
        if (node < N) {
            int d = min(sCnt[tid], 64);
            deg[node] = d;
            int p8 = (d + 7) & ~7;
            for (int s = d; s < p8; s++)
                ell[(size_t)node * 64 + s] = (unsigned short)N;
        }
    }
}

// Aggregation: wave per node PAIR; lanes 0-31 = node A (32 uint channel-pairs),
// lanes 32-63 = node B. Each neighbor load covers both rows (256B), 8-unrolled.
// hin fp16 (N+1 rows, row N = zeros). Writes V fp32 (post epilogue transform).
// FIRST:  v = relu(own + sum + b1a)
// !FIRST: v = sc*(own+sum) + (1+deg)*sh
template <bool FIRST>
__global__ __launch_bounds__(256, 8) void agg_kernel(
    const unsigned short* __restrict__ hin, const unsigned short* __restrict__ ell,
    const int* __restrict__ deg,
    const float* __restrict__ statsPrev, const float* __restrict__ gamma,
    const float* __restrict__ beta, const float* __restrict__ bias0,
    float* __restrict__ vout)
{
    int tid = threadIdx.x, lane = tid & 63, wv = tid >> 6;
    int la = lane & 31, half = lane >> 5;
    const unsigned* hinU = (const unsigned*)hin;

    // epilogue params for channels 2la, 2la+1
    float sc0 = 1.f, sc1 = 1.f, sh0 = 0.f, sh1 = 0.f, b00 = 0.f, b01 = 0.f;
    if constexpr (FIRST) {
        float2 b = *(const float2*)(bias0 + 2 * la);
        b00 = b.x; b01 = b.y;
    } else {
        float s10 = 0.f, s11 = 0.f, s20 = 0.f, s21 = 0.f;
#pragma unroll
        for (int s = 0; s < SSPLIT; s++) {
            float2 a = *(const float2*)(statsPrev + s * 128 + 2 * la);
            float2 b = *(const float2*)(statsPrev + s * 128 + 64 + 2 * la);
            s10 += a.x; s11 += a.y; s20 += b.x; s21 += b.y;
        }
        float2 g = *(const float2*)(gamma + 2 * la);
        float2 be = *(const float2*)(beta + 2 * la);
        float m0 = s10 / N, m1 = s11 / N;
        sc0 = g.x * rsqrtf(s20 / N - m0 * m0 + BN_EPS);
        sc1 = g.y * rsqrtf(s21 / N - m1 * m1 + BN_EPS);
        sh0 = be.x - m0 * sc0;
        sh1 = be.y - m1 * sc1;
    }

    int wid = blockIdx.x * 4 + wv;
    int nW = gridDim.x * 4;
    int nPairs = (N + 1) / 2;

    for (int pair = wid; pair < nPairs; pair += nW) {
        int nA = 2 * pair;
        int nB = 2 * pair + 1;
        bool hasB = nB < N;
        int dA = deg[nA];
        int dB = hasB ? deg[nB] : 0;
        const unsigned short* rA = ell + (size_t)nA * 64;
        const unsigned short* rB = ell + (size_t)(hasB ? nB : nA) * 64;
        int idxA = rA[lane];
        int idxB = rB[lane];
        int pA = (dA + 7) & ~7;
        int pB = hasB ? ((dB + 7) & ~7) : 0;
        int pm = max(pA, pB);

        int nSel = half ? (hasB ? nB : N) : nA;
        float2 ov = h2f2(hinU[(size_t)nSel * 32 + la]);
        float a0 = ov.x, a1 = ov.y;

        for (int g = 0; g < pm; g += 8) {
            unsigned vv[8];
#pragma unroll
            for (int t = 0; t < 8; t++) {
                int sA = (g + t < pA) ? __builtin_amdgcn_readlane(idxA, g + t) : N;
                int sB = (g + t < pB) ? __builtin_amdgcn_readlane(idxB, g + t) : N;
                int s = half ? sB : sA;
                vv[t] = hinU[(size_t)s * 32 + la];
            }
            float2 f0 = h2f2(vv[0]), f1 = h2f2(vv[1]), f2 = h2f2(vv[2]), f3 = h2f2(vv[3]);
            float2 f4 = h2f2(vv[4]), f5 = h2f2(vv[5]), f6 = h2f2(vv[6]), f7 = h2f2(vv[7]);
            a0 += ((f0.x + f1.x) + (f2.x + f3.x)) + ((f4.x + f5.x) + (f6.x + f7.x));
            a1 += ((f0.y + f1.y) + (f2.y + f3.y)) + ((f4.y + f5.y) + (f6.y + f7.y));
        }

        float v0, v1;
        if constexpr (FIRST) {
            v0 = fmaxf(a0 + b00, 0.f);
            v1 = fmaxf(a1 + b01, 0.f);
        } else {
            int dsel = half ? dB : dA;
            float dsh = (float)(1 + dsel);
            v0 = sc0 * a0 + dsh * sh0;
            v1 = sc1 * a1 + dsh * sh1;
        }
        if (nSel < N)
            *(float2*)(vout + (size_t)nSel * 64 + 2 * la) = make_float2(v0, v1);
    }
}

// MLP on V tiles: FIRST: O = relu(V@W2+b2). !FIRST: H=relu(V@W1+b1); O=relu(H@W2+b2).
// Store hout fp16, accumulate BN stats.
template <bool FIRST>
__global__ __launch_bounds__(256) void mlp_kernel(
    const float* __restrict__ V,
    const float* __restrict__ W1, const float* __restrict__ b1,
    const float* __restrict__ W2, const float* __restrict__ b2,
    unsigned short* __restrict__ hout, float* __restrict__ statsOut)
{
    __shared__ float sV[64 * 68];
    __shared__ float sStat[128];

    int tid = threadIdx.x;
    if (tid < 128) sStat[tid] = 0.f;
    int base = blockIdx.x * 64;

    for (int i = tid; i < 1024; i += 256) {
        int r = i >> 4, c4 = i & 15;
        float4 val = make_float4(0.f, 0.f, 0.f, 0.f);
        if (base + r < N) val = ld4(V + (size_t)(base + r) * 64 + c4 * 4);
        st4(sV + r * 68 + c4 * 4, val);
    }
    __syncthreads();

    int ty = tid >> 4, tx = tid & 15;

    if constexpr (!FIRST) {
        float acc[4][4];
#pragma unroll
        for (int cc = 0; cc < 4; cc++) {
            float b = b1[4 * tx + cc];
            acc[0][cc] = b; acc[1][cc] = b; acc[2][cc] = b; acc[3][cc] = b;
        }
#pragma unroll 4
        for (int c = 0; c < 64; c++) {
            float4 w4 = ld4(W1 + c * 64 + 4 * tx);
#pragma unroll
            for (int r = 0; r < 4; r++) {
                float a = sV[(4 * ty + r) * 68 + c];
                acc[r][0] += a * w4.x; acc[r][1] += a * w4.y;
                acc[r][2] += a * w4.z; acc[r][3] += a * w4.w;
            }
        }
        __syncthreads();
#pragma unroll
        for (int r = 0; r < 4; r++)
            st4(sV + (4 * ty + r) * 68 + 4 * tx,
                make_float4(fmaxf(acc[r][0], 0.f), fmaxf(acc[r][1], 0.f),
                            fmaxf(acc[r][2], 0.f), fmaxf(acc[r][3], 0.f)));
        __syncthreads();
    }

    float acc[4][4];
#pragma unroll
    for (int cc = 0; cc < 4; cc++) {
        float b = b2[4 * tx + cc];
        acc[0][cc] = b; acc[1][cc] = b; acc[2][cc] = b; acc[3][cc] = b;
    }
#pragma unroll 4
    for (int c = 0; c < 64; c++) {
        float4 w4 = ld4(W2 + c * 64 + 4 * tx);
#pragma unroll
        for (int r = 0; r < 4; r++) {
            float a = sV[(4 * ty + r) * 68 + c];
            acc[r][0] += a * w4.x; acc[r][1] += a * w4.y;
            acc[r][2] += a * w4.z; acc[r][3] += a * w4.w;
        }
    }
#pragma unroll
    for (int r = 0; r < 4; r++) {
        int node = base + 4 * ty + r;
        if (node < N) {
            float o0 = fmaxf(acc[r][0], 0.f), o1 = fmaxf(acc[r][1], 0.f);
            float o2 = fmaxf(acc[r][2], 0.f), o3 = fmaxf(acc[r][3], 0.f);
            acc[r][0] = o0; acc[r][1] = o1; acc[r][2] = o2; acc[r][3] = o3;
            ushort4 s;
            s.x = f2h(o0); s.y = f2h(o1); s.z = f2h(o2); s.w = f2h(o3);
            *(ushort4*)(hout + (size_t)node * 64 + 4 * tx) = s;
        } else {
            acc[r][0] = acc[r][1] = acc[r][2] = acc[r][3] = 0.f;
        }
    }
#pragma unroll
    for (int cc = 0; cc < 4; cc++) {
        float s = 0.f, q = 0.f;
#pragma unroll
        for (int r = 0; r < 4; r++) { s += acc[r][cc]; q += acc[r][cc] * acc[r][cc]; }
        atomicAdd(&sStat[4 * tx + cc], s);
        atomicAdd(&sStat[64 + 4 * tx + cc], q);
    }
    __syncthreads();
    if (tid < 128)
        atomicAdd(&statsOut[(blockIdx.x & (SSPLIT - 1)) * 128 + tid], sStat[tid]);
}

// pooled[g] = sc*sum_{n in g} h[n] + cnt*sh; z=relu(p@fc1+b1); z@fc2+b2; log_softmax
__global__ __launch_bounds__(1024) void pool_head_kernel(
    const unsigned short* __restrict__ h, const int* __restrict__ batch,
    const float* __restrict__ stats, const float* __restrict__ gamma, const float* __restrict__ beta,
    const float* __restrict__ fc1w, const float* __restrict__ fc1b,
    const float* __restrict__ fc2w, const float* __restrict__ fc2b,
    float* __restrict__ out)
{
    __shared__ float sacc[16][64];
    __shared__ float sp[64];
    __shared__ float sz[64];
    __shared__ float so[10];

    int g = blockIdx.x;
    int lane = threadIdx.x & 63, wv = threadIdx.x >> 6;

    int start, end;
    {
        int lo = 0, hi = N;
        while (lo < hi) { int mid = (lo + hi) >> 1; if (batch[mid] < g) lo = mid + 1; else hi = mid; }
        start = lo;
        lo = start; hi = N;
        while (lo < hi) { int mid = (lo + hi) >> 1; if (batch[mid] < g + 1) lo = mid + 1; else hi = mid; }
        end = lo;
    }

    float acc = 0.f;
    for (int node = start + wv; node < end; node += 16)
        acc += h2f(h[(size_t)node * 64 + lane]);
    sacc[wv][lane] = acc;
    __syncthreads();

    if (wv == 0) {
        float s1 = 0.f, s2 = 0.f;
#pragma unroll
        for (int s = 0; s < SSPLIT; s++) {
            s1 += stats[s * 128 + lane];
            s2 += stats[s * 128 + 64 + lane];
        }
        float mean = s1 * (1.f / N);
        float var  = s2 * (1.f / N) - mean * mean;
        float sc = gamma[lane] * rsqrtf(var + BN_EPS);
        float sh = beta[lane] - mean * sc;
        float t = 0.f;
#pragma unroll
        for (int w = 0; w < 16; w++) t += sacc[w][lane];
        sp[lane] = sc * t + (float)(end - start) * sh;
    }
    __syncthreads();
    if (wv == 0) {
        float a = fc1b[lane];
#pragma unroll
        for (int c = 0; c < 64; c++) a += sp[c] * fc1w[c * 64 + lane];
        sz[lane] = fmaxf(a, 0.f);
    }
    __syncthreads();
    if (wv == 0 && lane < 10) {
        float z = fc2b[lane];
#pragma unroll
        for (int j = 0; j < 64; j++) z += sz[j] * fc2w[j * 10 + lane];
        so[lane] = z;
    }
    __syncthreads();
    if (wv == 0 && lane < 10) {
        float m = -1e30f;
#pragma unroll
        for (int c = 0; c < 10; c++) m = fmaxf(m, so[c]);
        float s = 0.f;
#pragma unroll
        for (int c = 0; c < 10; c++) s += expf(so[c] - m);
        out[g * 10 + lane] = so[lane] - m - logf(s);
    }
}

extern "C" void kernel_launch(void* const* d_in, const int* in_sizes, int n_in,
                              void* d_out, int out_size, void* d_ws, size_t ws_size,
                              hipStream_t stream)
{
    const float* x    = (const float*)d_in[0];
    const int*   ei   = (const int*)  d_in[1];
    const int*   batch= (const int*)  d_in[2];
    const float* W1a  = (const float*)d_in[3];
    const float* b1a  = (const float*)d_in[4];
    const float* W1b  = (const float*)d_in[5];
    const float* b1b  = (const float*)d_in[6];
    const float* Wa   = (const float*)d_in[7];
    const float* ba   = (const float*)d_in[8];
    const float* Wb   = (const float*)d_in[9];
    const float* bb   = (const float*)d_in[10];
    const float* gammas = (const float*)d_in[11];
    const float* betas  = (const float*)d_in[12];
    const float* fc1w = (const float*)d_in[13];
    const float* fc1b = (const float*)d_in[14];
    const float* fc2w = (const float*)d_in[15];
    const float* fc2b = (const float*)d_in[16];
    float* out = (float*)d_out;

    // workspace carve (offsets 256-aligned)
    char* w = (char*)d_ws;
    int*            cnt   = (int*)w;                          // @0         4096     (zeroed)
    float*          stats = (float*)(w + 4096);               // @4096      40960    (zeroed)
    unsigned*       bkt   = (unsigned*)(w + 45056);           // @45056     4003840
    unsigned short* ell   = (unsigned short*)(w + 4048896);   // @4048896   6400000
    int*            deg   = (int*)(w + 10448896);             // @10448896  200192
    unsigned short* bufA  = (unsigned short*)(w + 10649088);  // @10649088  6400256 ((N+1)*64 fp16)
    unsigned short* bufB  = (unsigned short*)(w + 17049344);  // @17049344  6400256
    float*          V     = (float*)(w + 23449600);           // @23449600  12800000 (N*64 f32)

    hipMemsetAsync(d_ws, 0, 45056, stream);                          // cnt + stats
    hipMemsetAsync(bufA + (size_t)N * 64, 0, 128, stream);           // zero row N
    hipMemsetAsync(bufB + (size_t)N * 64, 0, 128, stream);

    int EB = (E + 255) / 256;            // 3125 edge blocks
    prep_kernel<<<EB + NB, 256, 0, stream>>>(ei, cnt, bkt, x, W1a, bufA, EB);
    conv_kernel<<<NB, 256, 0, stream>>>(bkt, cnt, ell, deg);

    const int SST = SSPLIT * 128;
    const int AGB = 2048;                // agg grid: 8 blocks/CU

    // layer 1
    agg_kernel<true><<<AGB, 256, 0, stream>>>(
        bufA, ell, deg, nullptr, nullptr, nullptr, b1a, V);
    mlp_kernel<true><<<NB, 256, 0, stream>>>(
        V, nullptr, nullptr, W1b, b1b, bufB, stats);

    // layers 2..5: layer i+2 reads h of layer i+1, folds BN_i (gammas[i])
    for (int i = 0; i < 4; i++) {
        const unsigned short* hin = (i & 1) ? bufA : bufB;
        unsigned short* hout      = (i & 1) ? bufB : bufA;
        agg_kernel<false><<<AGB, 256, 0, stream>>>(
            hin, ell, deg, stats + i * SST, gammas + 64 * i, betas + 64 * i,
            nullptr, V);
        mlp_kernel<false><<<NB, 256, 0, stream>>>(
            V, Wa + 4096 * i, ba + 64 * i, Wb + 4096 * i, bb + 64 * i,
            hout, stats + (i + 1) * SST);
    }

    // final h is in bufB (layer5: i=3 -> hout = bufB); fold BN_4 (gammas[4])
    pool_head_kernel<<<G, 1024, 0, stream>>>(
        bufB, batch, stats + 4 * SST, gammas + 256, betas + 256,
        fc1w, fc1b, fc2w, fc2b, out);
}